// Round 2
// baseline (908.792 us; speedup 1.0000x reference)
//
#include <hip/hip_runtime.h>
#include <hip/hip_bf16.h>

#define DEV __device__ __forceinline__

DEV float siluf(float x){ return x / (1.f + expf(-x)); }

DEV float wredsum(float v){
  #pragma unroll
  for(int m = 32; m; m >>= 1) v += __shfl_xor(v, m);
  return v;
}

// ---- stats layout (float offsets within stats block) ----
#define S1 0
#define Q1 16
#define S2 32
#define Q2 64
#define S3 96
#define Q3 160
#define S4 224
#define Q4 288
#define S5 352
#define Q5 416
#define SLOSS 480
#define NSTATF 512

// =========================================================================
// K_prep: transpose enc_w3 [64][32][25] -> w3t [(i*25+k)*64 + c]
//         transpose dec_wt [64][64][25] -> dwtt [(i*25+k)*64 + o]
__global__ void k_prep(const float* ew3, const float* dwt, float* w3t, float* dwtt){
  const int n1 = 64*32*25, n2 = 64*64*25;
  for(int i = blockIdx.x*blockDim.x + threadIdx.x; i < n1+n2; i += gridDim.x*blockDim.x){
    if(i < n1){
      int c = i/(32*25), r = i - c*(32*25), ii = r/25, k = r - ii*25;
      w3t[(ii*25 + k)*64 + c] = ew3[i];
    } else {
      int j = i - n1;
      int ii = j/(64*25), r = j - ii*(64*25), o = r/25, k = r - o*25;
      dwtt[(ii*25 + k)*64 + o] = dwt[j];
    }
  }
}

// =========================================================================
// K1: conv1 (1->16, K=5, pad2) + silu + bn1 stats
__global__ void k1(const float* __restrict__ x, const float* __restrict__ w1,
                   const float* __restrict__ b1, float* __restrict__ h1, float* stats){
  __shared__ float xs[260];
  __shared__ float ssum[16], ssq[16];
  int tid = threadIdx.x, b = blockIdx.y, t0 = blockIdx.x*256;
  if(tid < 16){ ssum[tid] = 0.f; ssq[tid] = 0.f; }
  for(int i = tid; i < 260; i += 256){
    int t = t0 + i - 2;
    xs[i] = (t >= 0 && t < 10240) ? x[b*10240 + t] : 0.f;
  }
  __syncthreads();
  int t = t0 + tid;
  #pragma unroll
  for(int c = 0; c < 16; c++){
    float a = b1[c];
    #pragma unroll
    for(int k = 0; k < 5; k++) a = fmaf(w1[c*5+k], xs[tid+k], a);
    a = siluf(a);
    h1[((b*16 + c)*10240) + t] = a;
    float s = wredsum(a), s2 = wredsum(a*a);
    if((tid & 63) == 0){ atomicAdd(&ssum[c], s); atomicAdd(&ssq[c], s2); }
  }
  __syncthreads();
  if(tid < 16){ atomicAdd(stats+S1+tid, ssum[tid]); atomicAdd(stats+Q1+tid, ssq[tid]); }
}

// =========================================================================
// K2: bn1 normalize + conv2 (16->32, K=5, pad2) + silu + bn2 stats
__global__ void k2(const float* __restrict__ h1, const float* __restrict__ w2,
                   const float* __restrict__ b2, const float* __restrict__ g1,
                   const float* __restrict__ bb1, float* __restrict__ h2out, float* stats){
  __shared__ float hs[16*264];
  __shared__ float wl[2560];
  __shared__ float A1[16], B1[16];
  __shared__ float ssum[32], ssq[32];
  int tid = threadIdx.x, b = blockIdx.y, t0 = blockIdx.x*256;
  for(int i = tid; i < 2560; i += 256) wl[i] = w2[i];
  if(tid < 16){
    float mu = stats[S1+tid]/81920.f;
    float var = stats[Q1+tid]/81920.f - mu*mu;
    float rs = rsqrtf(var + 1e-5f);
    A1[tid] = rs*g1[tid];
    B1[tid] = bb1[tid] - mu*rs*g1[tid];
  }
  if(tid < 32){ ssum[tid] = 0.f; ssq[tid] = 0.f; }
  __syncthreads();
  for(int i = tid; i < 16*260; i += 256){
    int ch = i/260, tt = i - ch*260;
    int t = t0 + tt - 2;
    hs[ch*264 + tt] = (t >= 0 && t < 10240) ? (h1[((b*16+ch)*10240)+t]*A1[ch] + B1[ch]) : 0.f;
  }
  __syncthreads();
  int t = t0 + tid;
  float acc[32];
  #pragma unroll
  for(int c = 0; c < 32; c++) acc[c] = b2[c];
  for(int i = 0; i < 16; i++){
    float z0 = hs[i*264+tid], z1 = hs[i*264+tid+1], z2 = hs[i*264+tid+2],
          z3 = hs[i*264+tid+3], z4 = hs[i*264+tid+4];
    #pragma unroll
    for(int c = 0; c < 32; c++){
      const float* wp = &wl[(c*16+i)*5];
      acc[c] = fmaf(wp[0],z0,fmaf(wp[1],z1,fmaf(wp[2],z2,fmaf(wp[3],z3,fmaf(wp[4],z4,acc[c])))));
    }
  }
  #pragma unroll
  for(int c = 0; c < 32; c++){
    float a = siluf(acc[c]);
    h2out[((b*32 + c)*10240) + t] = a;
    float s = wredsum(a), s2 = wredsum(a*a);
    if((tid & 63) == 0){ atomicAdd(&ssum[c], s); atomicAdd(&ssq[c], s2); }
  }
  __syncthreads();
  if(tid < 32){ atomicAdd(stats+S2+tid, ssum[tid]); atomicAdd(stats+Q2+tid, ssq[tid]); }
}

// =========================================================================
// K3: bn2 normalize + conv3 (32->64, K=25, stride5, pad12) + tanh + bn3 stats
// stride-5 conv decomposed into 5 phase-convs (kk = k mod 5).
__global__ void k3(const float* __restrict__ h2, const float* __restrict__ w3t,
                   const float* __restrict__ eb3, const float* __restrict__ g2,
                   const float* __restrict__ bb2, float* __restrict__ zn, float* stats){
  __shared__ float X[5*32*40];
  __shared__ float A2[32], B2[32];
  __shared__ float ssum[64], ssq[64];
  int tid = threadIdx.x, b = blockIdx.y, l0 = blockIdx.x*32;
  if(tid < 32){
    float mu = stats[S2+tid]/81920.f;
    float var = stats[Q2+tid]/81920.f - mu*mu;
    float rs = rsqrtf(var + 1e-5f);
    A2[tid] = rs*g2[tid];
    B2[tid] = bb2[tid] - mu*rs*g2[tid];
  }
  if(tid < 64){ ssum[tid] = 0.f; ssq[tid] = 0.f; }
  __syncthreads();
  // X[kk][ch][m] = normalized h2 at t = 5*(l0+m) + kk - 12
  for(int i2 = tid; i2 < 5*32*36; i2 += 256){
    int kk = i2/(32*36);
    int r  = i2 - kk*(32*36);
    int ch = r/36, m = r - ch*36;
    int t = 5*(l0 + m) + kk - 12;
    float v = 0.f;
    if(t >= 0 && t < 10240) v = h2[((b*32+ch)*10240)+t]*A2[ch] + B2[ch];
    X[(kk*32+ch)*40 + m] = v;
  }
  __syncthreads();
  int c = tid & 63, lslot = tid >> 6;
  float acc[8];
  float bias = eb3[c];
  #pragma unroll
  for(int s = 0; s < 8; s++) acc[s] = bias;
  for(int i = 0; i < 32; i++){
    #pragma unroll
    for(int kk = 0; kk < 5; kk++){
      float z[12];
      #pragma unroll
      for(int j = 0; j < 12; j++) z[j] = X[(kk*32+i)*40 + lslot*8 + j];
      #pragma unroll
      for(int kap = 0; kap < 5; kap++){
        float w = w3t[(i*25 + kap*5 + kk)*64 + c];
        #pragma unroll
        for(int s = 0; s < 8; s++) acc[s] = fmaf(w, z[s+kap], acc[s]);
      }
    }
  }
  float ls = 0.f, lq = 0.f;
  #pragma unroll
  for(int s = 0; s < 8; s++){
    int l = l0 + lslot*8 + s;
    float a = tanhf(acc[s]);
    zn[((b*2048 + l)*64) + c] = a;
    ls += a; lq += a*a;
  }
  atomicAdd(&ssum[c], ls); atomicAdd(&ssq[c], lq);
  __syncthreads();
  if(tid < 64){ atomicAdd(stats+S3+tid, ssum[tid]); atomicAdd(stats+Q3+tid, ssq[tid]); }
}

// =========================================================================
// K3b: bn3 normalize zn in place
__global__ void k3b(float* zn, const float* g3, const float* b3, const float* stats){
  __shared__ float A[64], B[64];
  int tid = threadIdx.x;
  if(tid < 64){
    float mu = stats[S3+tid]/16384.f;
    float var = stats[Q3+tid]/16384.f - mu*mu;
    float rs = rsqrtf(var + 1e-5f);
    A[tid] = rs*g3[tid];
    B[tid] = b3[tid] - mu*rs*g3[tid];
  }
  __syncthreads();
  for(int i = blockIdx.x*256 + tid; i < 16384*64; i += gridDim.x*256){
    int c = i & 63;
    zn[i] = zn[i]*A[c] + B[c];
  }
}

// =========================================================================
// K5: VQ argmin over 8192 codes + commit-loss accumulation.
// 64 rows/block, LDS tiles XOR-swizzled for conflict-free float4 reads.
__global__ void k5(const float* __restrict__ zn, const float* __restrict__ cb,
                   int* __restrict__ idx_out, float* stats, float* __restrict__ out_idx){
  __shared__ __align__(16) float zt[64*64];
  __shared__ __align__(16) float ct[64*64];
  __shared__ float cnl[64];
  __shared__ float redd[64*16];
  __shared__ int   redi[64*16];
  __shared__ int   fbi[64];
  __shared__ float lacc;
  int tid = threadIdx.x;
  int R0 = blockIdx.x * 64;
  { // stage z tile (swizzled)
    int row = tid >> 2, part = tid & 3;
    #pragma unroll
    for(int j = 0; j < 4; j++){
      int kb = part + 4*j;
      float4 v = *(const float4*)(zn + (size_t)(R0+row)*64 + kb*4);
      *(float4*)(zt + row*64 + 4*(kb ^ (row>>2))) = v;
    }
  }
  float bestd[4]; int besti[4];
  #pragma unroll
  for(int i = 0; i < 4; i++){ bestd[i] = 3.4e38f; besti[i] = 0; }
  int rslot = tid >> 4, cslot = tid & 15;
  int r0 = rslot*4;
  for(int tile = 0; tile < 128; ++tile){
    __syncthreads();
    { // stage code tile + norms
      int row = tid >> 2, part = tid & 3;
      int code = tile*64 + row;
      float pn = 0.f;
      #pragma unroll
      for(int j = 0; j < 4; j++){
        int kb = part + 4*j;
        float4 v = *(const float4*)(cb + (size_t)code*64 + kb*4);
        pn += v.x*v.x + v.y*v.y + v.z*v.z + v.w*v.w;
        *(float4*)(ct + row*64 + 4*(kb ^ (row>>2))) = v;
      }
      pn += __shfl_xor(pn, 1); pn += __shfl_xor(pn, 2);
      if(part == 0) cnl[row] = pn;
    }
    __syncthreads();
    float acc[4][4];
    #pragma unroll
    for(int i = 0; i < 4; i++)
      #pragma unroll
      for(int j = 0; j < 4; j++) acc[i][j] = 0.f;
    #pragma unroll
    for(int kk = 0; kk < 16; kk++){
      float4 za[4], ca[4];
      #pragma unroll
      for(int i = 0; i < 4; i++) za[i] = *(float4*)(zt + (r0+i)*64 + 4*(kk ^ rslot));
      #pragma unroll
      for(int j = 0; j < 4; j++) ca[j] = *(float4*)(ct + (4*cslot+j)*64 + 4*(kk ^ cslot));
      #pragma unroll
      for(int i = 0; i < 4; i++)
        #pragma unroll
        for(int j = 0; j < 4; j++)
          acc[i][j] = fmaf(za[i].w, ca[j].w, fmaf(za[i].z, ca[j].z,
                      fmaf(za[i].y, ca[j].y, fmaf(za[i].x, ca[j].x, acc[i][j]))));
    }
    #pragma unroll
    for(int j = 0; j < 4; j++){
      int c = tile*64 + 4*cslot + j;
      float cn = cnl[4*cslot + j];
      #pragma unroll
      for(int i = 0; i < 4; i++){
        float d = cn - 2.f*acc[i][j];
        if(d < bestd[i]){ bestd[i] = d; besti[i] = c; }
      }
    }
  }
  __syncthreads();
  #pragma unroll
  for(int i = 0; i < 4; i++){ redd[(r0+i)*16 + cslot] = bestd[i]; redi[(r0+i)*16 + cslot] = besti[i]; }
  if(tid == 0) lacc = 0.f;
  __syncthreads();
  if(tid < 64){
    float bd = redd[tid*16]; int bi = redi[tid*16];
    #pragma unroll
    for(int s = 1; s < 16; s++){
      float d = redd[tid*16 + s]; int ii = redi[tid*16 + s];
      if(d < bd || (d == bd && ii < bi)){ bd = d; bi = ii; }
    }
    fbi[tid] = bi;
    idx_out[R0 + tid] = bi;
    out_idx[R0 + tid] = (float)bi;   // f32 output
  }
  __syncthreads();
  { // commit loss: sum (q - z)^2 for the 64 rows
    int row = tid >> 2, part = tid & 3;
    int code = fbi[row];
    float s = 0.f;
    #pragma unroll
    for(int j = 0; j < 4; j++){
      int kb = part + 4*j;
      float4 q = *(const float4*)(cb + (size_t)code*64 + kb*4);
      float4 z = *(float4*)(zt + row*64 + 4*(kb ^ (row>>2)));
      float dx = q.x-z.x, dy = q.y-z.y, dz = q.z-z.z, dw = q.w-z.w;
      s += dx*dx + dy*dy + dz*dz + dw*dw;
    }
    float tot = wredsum(s);
    if((tid & 63) == 0) atomicAdd(&lacc, tot);
    __syncthreads();
    if(tid == 0) atomicAdd(stats + SLOSS, lacc);
  }
}

// =========================================================================
// K6: finalize commit loss (f32 output)
__global__ void k6(const float* stats, float* out){
  if(threadIdx.x == 0) out[0] = 2.f * stats[SLOSS] / 1048576.f;
}

// =========================================================================
// K7: transposed conv (lhs_dilation=5, pad12, K=25) via 5 phase-convs
//     + silu + dbn1 stats. Output in phase layout h4p[v][b][c][u].
__global__ void k7(const int* __restrict__ idxp, const float* __restrict__ cb,
                   const float* __restrict__ dwtt, float* __restrict__ h4p, float* stats){
  __shared__ float zq[64*40];
  __shared__ float tb[5*64*33];
  __shared__ float ssum[64], ssq[64];
  int tid = threadIdx.x, b = blockIdx.y, u0 = blockIdx.x*32;
  if(tid < 64){ ssum[tid] = 0.f; ssq[tid] = 0.f; }
  { // stage quantized vectors for u-window [u0-2, u0+34]
    int i = tid & 63, ms = tid >> 6;
    for(int m = ms; m < 37; m += 4){
      int u2 = u0 - 2 + m;
      float v = 0.f;
      if(u2 >= 0 && u2 < 2048){
        int code = idxp[b*2048 + u2];
        v = cb[(size_t)code*64 + i];
      }
      zq[i*40 + m] = v;
    }
  }
  __syncthreads();
  int c = tid & 63, uslot = tid >> 6;
  float acc[5][8];
  #pragma unroll
  for(int v = 0; v < 5; v++)
    #pragma unroll
    for(int s = 0; s < 8; s++) acc[v][s] = 0.f;
  const int km[5] = {2,3,4,0,1};
  const int ov[5] = {2,2,2,3,3};
  for(int i = 0; i < 64; i++){
    float z[13];
    #pragma unroll
    for(int j = 0; j < 13; j++) z[j] = zq[i*40 + uslot*8 + j];
    #pragma unroll
    for(int v = 0; v < 5; v++){
      #pragma unroll
      for(int r = 0; r < 5; r++){
        int k = km[v] + 5*r;
        float w = dwtt[(i*25 + k)*64 + c];
        int off = ov[v] - r + 2;   // 0..5, compile-time after unroll
        #pragma unroll
        for(int s = 0; s < 8; s++) acc[v][s] = fmaf(w, z[s+off], acc[v][s]);
      }
    }
  }
  float ls = 0.f, lq = 0.f;
  #pragma unroll
  for(int v = 0; v < 5; v++){
    #pragma unroll
    for(int s = 0; s < 8; s++){
      int u = u0 + uslot*8 + s;
      float a = siluf(acc[v][s]);
      tb[(v*64 + c)*33 + uslot*8 + s] = a;
      if(v == 0 || u < 2047){ ls += a; lq += a*a; }   // t=5u+v < 10236 validity
    }
  }
  atomicAdd(&ssum[c], ls); atomicAdd(&ssq[c], lq);
  __syncthreads();
  if(tid < 64){ atomicAdd(stats+S4+tid, ssum[tid]); atomicAdd(stats+Q4+tid, ssq[tid]); }
  // coalesced store from transpose buffer
  #pragma unroll
  for(int j = 0; j < 40; j++){
    int flat = tid + 256*j;
    int v = flat / 2048;
    int r = flat - v*2048;
    int cc = r >> 5, ur = r & 31;
    int u = u0 + ur;
    if(v == 0 || u < 2047)
      h4p[(((size_t)v*8 + b)*64 + cc)*2048 + u] = tb[(v*64 + cc)*33 + ur];
  }
}

// =========================================================================
// K8: dbn1 normalize + conv (64->64, K=5, pad2) + bias + silu + dbn2 stats
__global__ void k8(const float* __restrict__ h4p, const float* __restrict__ w2d,
                   const float* __restrict__ b2d, const float* __restrict__ g4,
                   const float* __restrict__ bb4, float* __restrict__ h5, float* stats){
  __shared__ float hw[64*136];
  __shared__ float A4[64], B4[64];
  __shared__ float ssum[64], ssq[64];
  int tid = threadIdx.x, b = blockIdx.y, t0 = blockIdx.x*128;
  if(tid < 64){
    float mu = stats[S4+tid]/81888.f;
    float var = stats[Q4+tid]/81888.f - mu*mu;
    float rs = rsqrtf(var + 1e-5f);
    A4[tid] = rs*g4[tid];
    B4[tid] = bb4[tid] - mu*rs*g4[tid];
    ssum[tid] = 0.f; ssq[tid] = 0.f;
  }
  __syncthreads();
  for(int i2 = tid; i2 < 64*132; i2 += 256){
    int ch = i2/132, tt = i2 - ch*132;
    int t = t0 + tt - 2;
    float v = 0.f;
    if(t >= 0 && t < 10236){
      int vv = t % 5, u = t / 5;
      v = h4p[(((size_t)vv*8 + b)*64 + ch)*2048 + u]*A4[ch] + B4[ch];
    }
    hw[ch*136 + tt] = v;
  }
  __syncthreads();
  int t_rel = tid & 127;
  int chalf = __builtin_amdgcn_readfirstlane(tid >> 7); // wave-uniform -> SGPR weight loads
  int t = t0 + t_rel;
  float acc[32];
  #pragma unroll
  for(int cc = 0; cc < 32; cc++) acc[cc] = b2d[chalf*32 + cc];
  for(int i = 0; i < 64; i++){
    float z0 = hw[i*136 + t_rel],     z1 = hw[i*136 + t_rel + 1],
          z2 = hw[i*136 + t_rel + 2], z3 = hw[i*136 + t_rel + 3],
          z4 = hw[i*136 + t_rel + 4];
    #pragma unroll
    for(int cc = 0; cc < 32; cc++){
      const float* wp = w2d + ((chalf*32 + cc)*64 + i)*5;
      acc[cc] = fmaf(wp[0],z0,fmaf(wp[1],z1,fmaf(wp[2],z2,fmaf(wp[3],z3,fmaf(wp[4],z4,acc[cc])))));
    }
  }
  bool valid = t < 10236;
  #pragma unroll
  for(int cc = 0; cc < 32; cc++){
    int cch = chalf*32 + cc;
    float a = siluf(acc[cc]);
    float av = valid ? a : 0.f;
    float s = wredsum(av), s2 = wredsum(av*av);
    if((tid & 63) == 0){ atomicAdd(&ssum[cch], s); atomicAdd(&ssq[cch], s2); }
    if(valid) h5[((size_t)(b*64 + cch))*10236 + t] = a;
  }
  __syncthreads();
  if(tid < 64){ atomicAdd(stats+S5+tid, ssum[tid]); atomicAdd(stats+Q5+tid, ssq[tid]); }
}

// =========================================================================
// K9: dbn2 normalize + 1x1 conv (64->1) + bias, pad to 10240, write f32 recon
__global__ void k9(const float* __restrict__ h5, const float* __restrict__ w3,
                   const float* __restrict__ b3, const float* __restrict__ g5,
                   const float* __restrict__ bb5, const float* stats,
                   float* __restrict__ out){
  __shared__ float WA[64], WB[64];
  int tid = threadIdx.x;
  if(tid < 64){
    float mu = stats[S5+tid]/81888.f;
    float var = stats[Q5+tid]/81888.f - mu*mu;
    float rs = rsqrtf(var + 1e-5f);
    float A = rs*g5[tid], B = bb5[tid] - mu*rs*g5[tid];
    float w = w3[tid];
    WA[tid] = w*A; WB[tid] = w*B;
  }
  __syncthreads();
  int b = blockIdx.y;
  int t = blockIdx.x*256 + tid;
  float acc = b3[0];
  if(t < 10236){
    const float* hp = h5 + (size_t)(b*64)*10236 + t;
    #pragma unroll
    for(int c = 0; c < 64; c++) acc += WA[c]*hp[(size_t)c*10236] + WB[c];
  } else acc = 0.f;
  out[b*10240 + t] = acc;
}

// =========================================================================
extern "C" void kernel_launch(void* const* d_in, const int* in_sizes, int n_in,
                              void* d_out, int out_size, void* d_ws, size_t ws_size,
                              hipStream_t stream){
  const float* x   = (const float*)d_in[0];
  const float* ew1 = (const float*)d_in[1];
  const float* eb1 = (const float*)d_in[2];
  const float* g1  = (const float*)d_in[3];
  const float* bb1 = (const float*)d_in[4];
  const float* ew2 = (const float*)d_in[5];
  const float* eb2 = (const float*)d_in[6];
  const float* g2  = (const float*)d_in[7];
  const float* bb2 = (const float*)d_in[8];
  const float* ew3 = (const float*)d_in[9];
  const float* eb3 = (const float*)d_in[10];
  const float* g3  = (const float*)d_in[11];
  const float* bb3 = (const float*)d_in[12];
  const float* cb  = (const float*)d_in[13];
  const float* dwt = (const float*)d_in[14];
  const float* g4  = (const float*)d_in[15];
  const float* bb4 = (const float*)d_in[16];
  const float* w2d = (const float*)d_in[17];
  const float* b2d = (const float*)d_in[18];
  const float* g5  = (const float*)d_in[19];
  const float* bb5 = (const float*)d_in[20];
  const float* w3d = (const float*)d_in[21];
  const float* b3d = (const float*)d_in[22];

  char* ws = (char*)d_ws;
  // layout (bytes): h4p overlaps h1/h2/zn (dead by decoder phase)
  float* h1   = (float*)(ws + 0);          // 5,242,880
  float* h2   = (float*)(ws + 5242880);    // 10,485,760
  float* zn   = (float*)(ws + 15728640);   // 4,194,304
  float* h4p  = (float*)(ws + 0);          // 20,971,520 (decoder phase)
  float* h5   = (float*)(ws + 20971520);   // 20,963,328
  float* w3t  = (float*)(ws + 41934848);   // 204,800
  float* dwtt = (float*)(ws + 42139648);   // 409,600
  int*   idxw = (int*)  (ws + 42549248);   // 65,536
  float* stats= (float*)(ws + 42614784);   // 2,048
  if(ws_size < 42616832) return;           // need ~40.6 MB scratch

  float* out = (float*)d_out;              // f32: [recon 81920][idx 16384][loss 1]

  hipMemsetAsync(stats, 0, NSTATF*4, stream);
  k_prep<<<600, 256, 0, stream>>>(ew3, dwt, w3t, dwtt);
  k1<<<dim3(40,8), 256, 0, stream>>>(x, ew1, eb1, h1, stats);
  k2<<<dim3(40,8), 256, 0, stream>>>(h1, ew2, eb2, g1, bb1, h2, stats);
  k3<<<dim3(64,8), 256, 0, stream>>>(h2, w3t, eb3, g2, bb2, zn, stats);
  k3b<<<1024, 256, 0, stream>>>(zn, g3, bb3, stats);
  k5<<<256, 256, 0, stream>>>(zn, cb, idxw, stats, out + 81920);
  k6<<<1, 64, 0, stream>>>(stats, out + 98304);
  k7<<<dim3(64,8), 256, 0, stream>>>(idxw, cb, dwtt, h4p, stats);
  k8<<<dim3(80,8), 256, 0, stream>>>(h4p, w2d, b2d, g4, bb4, h5, stats);
  k9<<<dim3(40,8), 256, 0, stream>>>(h5, w3d, b3d, g5, bb5, stats, out);
}

// Round 3
// 651.153 us; speedup vs baseline: 1.3957x; 1.3957x over previous
//
#include <hip/hip_runtime.h>
#include <hip/hip_bf16.h>

#define DEV __device__ __forceinline__

typedef __attribute__((ext_vector_type(8))) short s8v;     // 8 bf16 (4 VGPR)
typedef __attribute__((ext_vector_type(16))) float f32x16; // MFMA 32x32 acc

DEV float siluf(float x){ return x / (1.f + expf(-x)); }

DEV float wredsum(float v){
  #pragma unroll
  for(int m = 32; m; m >>= 1) v += __shfl_xor(v, m);
  return v;
}

DEV unsigned short bf16rne(float f){
  unsigned int u = __float_as_uint(f);
  u += 0x7FFFu + ((u >> 16) & 1u);
  return (unsigned short)(u >> 16);
}
DEV float bf16tof(unsigned short h){ return __uint_as_float(((unsigned int)h) << 16); }

// ---- stats layout (float offsets within stats block) ----
#define S1 0
#define Q1 16
#define S2 32
#define Q2 64
#define S3 96
#define Q3 160
#define S4 224
#define Q4 288
#define S5 352
#define Q5 416
#define SLOSS 480
#define NSTATF 512

#define EPSGAP 0.03125f

// =========================================================================
// K_prep: transpose enc_w3 [64][32][25] -> w3t [(i*25+k)*64 + c]
//         transpose dec_wt [64][64][25] -> dwtt [(i*25+k)*64 + o]
__global__ void k_prep(const float* ew3, const float* dwt, float* w3t, float* dwtt){
  const int n1 = 64*32*25, n2 = 64*64*25;
  for(int i = blockIdx.x*blockDim.x + threadIdx.x; i < n1+n2; i += gridDim.x*blockDim.x){
    if(i < n1){
      int c = i/(32*25), r = i - c*(32*25), ii = r/25, k = r - ii*25;
      w3t[(ii*25 + k)*64 + c] = ew3[i];
    } else {
      int j = i - n1;
      int ii = j/(64*25), r = j - ii*(64*25), o = r/25, k = r - o*25;
      dwtt[(ii*25 + k)*64 + o] = dwt[j];
    }
  }
}

// =========================================================================
// K_prep2: split codebook to bf16 hi/lo + f32 norms; zero rescore counter.
__global__ void k_prep2(const float* __restrict__ cb, unsigned short* __restrict__ cbh,
                        unsigned short* __restrict__ cbl, float* __restrict__ cnw,
                        int* cnt){
  if(blockIdx.x == 0 && threadIdx.x == 0) *cnt = 0;
  int j = blockIdx.x*256 + threadIdx.x;
  if(j < 8192){
    float nrm = 0.f;
    #pragma unroll
    for(int k = 0; k < 64; k += 4){
      float4 v = *(const float4*)(cb + (size_t)j*64 + k);
      float vv[4] = {v.x, v.y, v.z, v.w};
      #pragma unroll
      for(int c = 0; c < 4; c++){
        float x = vv[c];
        unsigned short hi = bf16rne(x);
        float lo = x - bf16tof(hi);
        cbh[(size_t)j*64 + k + c] = hi;
        cbl[(size_t)j*64 + k + c] = bf16rne(lo);
        nrm = fmaf(x, x, nrm);
      }
    }
    cnw[j] = nrm;
  }
}

// =========================================================================
// K1: conv1 (1->16, K=5, pad2) + silu + bn1 stats
__global__ void k1(const float* __restrict__ x, const float* __restrict__ w1,
                   const float* __restrict__ b1, float* __restrict__ h1, float* stats){
  __shared__ float xs[260];
  __shared__ float ssum[16], ssq[16];
  int tid = threadIdx.x, b = blockIdx.y, t0 = blockIdx.x*256;
  if(tid < 16){ ssum[tid] = 0.f; ssq[tid] = 0.f; }
  for(int i = tid; i < 260; i += 256){
    int t = t0 + i - 2;
    xs[i] = (t >= 0 && t < 10240) ? x[b*10240 + t] : 0.f;
  }
  __syncthreads();
  int t = t0 + tid;
  #pragma unroll
  for(int c = 0; c < 16; c++){
    float a = b1[c];
    #pragma unroll
    for(int k = 0; k < 5; k++) a = fmaf(w1[c*5+k], xs[tid+k], a);
    a = siluf(a);
    h1[((b*16 + c)*10240) + t] = a;
    float s = wredsum(a), s2 = wredsum(a*a);
    if((tid & 63) == 0){ atomicAdd(&ssum[c], s); atomicAdd(&ssq[c], s2); }
  }
  __syncthreads();
  if(tid < 16){ atomicAdd(stats+S1+tid, ssum[tid]); atomicAdd(stats+Q1+tid, ssq[tid]); }
}

// =========================================================================
// K2: bn1 normalize + conv2 (16->32, K=5, pad2) + silu + bn2 stats
__global__ void k2(const float* __restrict__ h1, const float* __restrict__ w2,
                   const float* __restrict__ b2, const float* __restrict__ g1,
                   const float* __restrict__ bb1, float* __restrict__ h2out, float* stats){
  __shared__ float hs[16*264];
  __shared__ float wl[2560];
  __shared__ float A1[16], B1[16];
  __shared__ float ssum[32], ssq[32];
  int tid = threadIdx.x, b = blockIdx.y, t0 = blockIdx.x*256;
  for(int i = tid; i < 2560; i += 256) wl[i] = w2[i];
  if(tid < 16){
    float mu = stats[S1+tid]/81920.f;
    float var = stats[Q1+tid]/81920.f - mu*mu;
    float rs = rsqrtf(var + 1e-5f);
    A1[tid] = rs*g1[tid];
    B1[tid] = bb1[tid] - mu*rs*g1[tid];
  }
  if(tid < 32){ ssum[tid] = 0.f; ssq[tid] = 0.f; }
  __syncthreads();
  for(int i = tid; i < 16*260; i += 256){
    int ch = i/260, tt = i - ch*260;
    int t = t0 + tt - 2;
    hs[ch*264 + tt] = (t >= 0 && t < 10240) ? (h1[((b*16+ch)*10240)+t]*A1[ch] + B1[ch]) : 0.f;
  }
  __syncthreads();
  int t = t0 + tid;
  float acc[32];
  #pragma unroll
  for(int c = 0; c < 32; c++) acc[c] = b2[c];
  for(int i = 0; i < 16; i++){
    float z0 = hs[i*264+tid], z1 = hs[i*264+tid+1], z2 = hs[i*264+tid+2],
          z3 = hs[i*264+tid+3], z4 = hs[i*264+tid+4];
    #pragma unroll
    for(int c = 0; c < 32; c++){
      const float* wp = &wl[(c*16+i)*5];
      acc[c] = fmaf(wp[0],z0,fmaf(wp[1],z1,fmaf(wp[2],z2,fmaf(wp[3],z3,fmaf(wp[4],z4,acc[c])))));
    }
  }
  #pragma unroll
  for(int c = 0; c < 32; c++){
    float a = siluf(acc[c]);
    h2out[((b*32 + c)*10240) + t] = a;
    float s = wredsum(a), s2 = wredsum(a*a);
    if((tid & 63) == 0){ atomicAdd(&ssum[c], s); atomicAdd(&ssq[c], s2); }
  }
  __syncthreads();
  if(tid < 32){ atomicAdd(stats+S2+tid, ssum[tid]); atomicAdd(stats+Q2+tid, ssq[tid]); }
}

// =========================================================================
// K3: bn2 normalize + conv3 (32->64, K=25, stride5, pad12) + tanh + bn3 stats
__global__ void k3(const float* __restrict__ h2, const float* __restrict__ w3t,
                   const float* __restrict__ eb3, const float* __restrict__ g2,
                   const float* __restrict__ bb2, float* __restrict__ zn, float* stats){
  __shared__ float X[5*32*40];
  __shared__ float A2[32], B2[32];
  __shared__ float ssum[64], ssq[64];
  int tid = threadIdx.x, b = blockIdx.y, l0 = blockIdx.x*32;
  if(tid < 32){
    float mu = stats[S2+tid]/81920.f;
    float var = stats[Q2+tid]/81920.f - mu*mu;
    float rs = rsqrtf(var + 1e-5f);
    A2[tid] = rs*g2[tid];
    B2[tid] = bb2[tid] - mu*rs*g2[tid];
  }
  if(tid < 64){ ssum[tid] = 0.f; ssq[tid] = 0.f; }
  __syncthreads();
  for(int i2 = tid; i2 < 5*32*36; i2 += 256){
    int kk = i2/(32*36);
    int r  = i2 - kk*(32*36);
    int ch = r/36, m = r - ch*36;
    int t = 5*(l0 + m) + kk - 12;
    float v = 0.f;
    if(t >= 0 && t < 10240) v = h2[((b*32+ch)*10240)+t]*A2[ch] + B2[ch];
    X[(kk*32+ch)*40 + m] = v;
  }
  __syncthreads();
  int c = tid & 63, lslot = tid >> 6;
  float acc[8];
  float bias = eb3[c];
  #pragma unroll
  for(int s = 0; s < 8; s++) acc[s] = bias;
  for(int i = 0; i < 32; i++){
    #pragma unroll
    for(int kk = 0; kk < 5; kk++){
      float z[12];
      #pragma unroll
      for(int j = 0; j < 12; j++) z[j] = X[(kk*32+i)*40 + lslot*8 + j];
      #pragma unroll
      for(int kap = 0; kap < 5; kap++){
        float w = w3t[(i*25 + kap*5 + kk)*64 + c];
        #pragma unroll
        for(int s = 0; s < 8; s++) acc[s] = fmaf(w, z[s+kap], acc[s]);
      }
    }
  }
  float ls = 0.f, lq = 0.f;
  #pragma unroll
  for(int s = 0; s < 8; s++){
    int l = l0 + lslot*8 + s;
    float a = tanhf(acc[s]);
    zn[((b*2048 + l)*64) + c] = a;
    ls += a; lq += a*a;
  }
  atomicAdd(&ssum[c], ls); atomicAdd(&ssq[c], lq);
  __syncthreads();
  if(tid < 64){ atomicAdd(stats+S3+tid, ssum[tid]); atomicAdd(stats+Q3+tid, ssq[tid]); }
}

// =========================================================================
// K3b: bn3 normalize zn in place
__global__ void k3b(float* zn, const float* g3, const float* b3, const float* stats){
  __shared__ float A[64], B[64];
  int tid = threadIdx.x;
  if(tid < 64){
    float mu = stats[S3+tid]/16384.f;
    float var = stats[Q3+tid]/16384.f - mu*mu;
    float rs = rsqrtf(var + 1e-5f);
    A[tid] = rs*g3[tid];
    B[tid] = b3[tid] - mu*rs*g3[tid];
  }
  __syncthreads();
  for(int i = blockIdx.x*256 + tid; i < 16384*64; i += gridDim.x*256){
    int c = i & 63;
    zn[i] = zn[i]*A[c] + B[c];
  }
}

// =========================================================================
// K5m: MFMA VQ distance pass (bf16 split, 3 MFMAs per K-16 step).
// Grid (4 chunks, 256 row-groups); block 256 thr = 4 waves, 64 rows x 2048 codes.
// Per wave: 32x32 quadrant via mfma_f32_32x32x16_bf16.
// C/D layout: col=lane&31, row=(reg&3)+8*(reg>>2)+4*(lane>>5)  [HW-verified]
// A/B layout: row|col=lane&31, k=8*(lane>>5)+i
__global__ __launch_bounds__(256) void k5m(const float* __restrict__ zn,
    const unsigned short* __restrict__ cbh, const unsigned short* __restrict__ cbl,
    const float* __restrict__ cnw, float* __restrict__ pbd, float* __restrict__ psd,
    int* __restrict__ pbi){
  int tid = threadIdx.x;
  int chunk = blockIdx.x;        // 0..3 -> codes [chunk*2048, +2048)
  int m0 = blockIdx.y * 64;      // row group
  int lane = tid & 63, widx = tid >> 6;
  int wr = widx >> 1, wc = widx & 1;
  int h = lane >> 5;
  int row = m0 + wr*32 + (lane & 31);

  // A (z) fragments: resident in registers for the whole kernel
  s8v ah[4], al[4];
  #pragma unroll
  for(int s = 0; s < 4; s++){
    int koff = s*16 + h*8;
    const float* zp = zn + (size_t)row*64 + koff;
    #pragma unroll
    for(int i = 0; i < 8; i++){
      float v = zp[i];
      unsigned short hi = bf16rne(v);
      float lo = v - bf16tof(hi);
      ah[s][i] = (short)hi;
      al[s][i] = (short)bf16rne(lo);
    }
  }

  float bd[16], sd[16]; int bi[16];
  #pragma unroll
  for(int r = 0; r < 16; r++){ bd[r] = 3.4e38f; sd[r] = 3.4e38f; bi[r] = 0; }
  f32x16 zv;
  #pragma unroll
  for(int i = 0; i < 16; i++) zv[i] = 0.f;

  int c0 = chunk * 2048;
  for(int it = 0; it < 32; ++it){
    int cbase = c0 + it*64 + wc*32;
    int col = cbase + (lane & 31);
    const short* bhp = (const short*)(cbh) + (size_t)col*64;
    const short* blp = (const short*)(cbl) + (size_t)col*64;
    s8v bh[4], bl[4];
    #pragma unroll
    for(int s = 0; s < 4; s++){
      bh[s] = *(const s8v*)(bhp + s*16 + h*8);
      bl[s] = *(const s8v*)(blp + s*16 + h*8);
    }
    float cnv = cnw[col];
    f32x16 a1 = __builtin_amdgcn_mfma_f32_32x32x16_bf16(ah[0], bh[0], zv, 0, 0, 0);
    f32x16 a2 = __builtin_amdgcn_mfma_f32_32x32x16_bf16(al[0], bh[0], zv, 0, 0, 0);
    a2 = __builtin_amdgcn_mfma_f32_32x32x16_bf16(ah[0], bl[0], a2, 0, 0, 0);
    #pragma unroll
    for(int s = 1; s < 4; s++){
      a1 = __builtin_amdgcn_mfma_f32_32x32x16_bf16(ah[s], bh[s], a1, 0, 0, 0);
      a2 = __builtin_amdgcn_mfma_f32_32x32x16_bf16(al[s], bh[s], a2, 0, 0, 0);
      a2 = __builtin_amdgcn_mfma_f32_32x32x16_bf16(ah[s], bl[s], a2, 0, 0, 0);
    }
    #pragma unroll
    for(int r = 0; r < 16; r++){
      float d = fmaf(-2.f, a1[r] + a2[r], cnv);
      bool take = d < bd[r];
      sd[r] = fminf(sd[r], fmaxf(d, bd[r]));
      bd[r] = take ? d : bd[r];
      bi[r] = take ? col : bi[r];
    }
  }

  // intra-wave merge across 32 cols (masks stay within 32-lane row-half groups)
  #pragma unroll
  for(int m = 1; m <= 16; m <<= 1){
    #pragma unroll
    for(int r = 0; r < 16; r++){
      float ob = __shfl_xor(bd[r], m);
      float os = __shfl_xor(sd[r], m);
      int   oi = __shfl_xor(bi[r], m);
      bool take = (ob < bd[r]) || (ob == bd[r] && oi < bi[r]);
      sd[r] = fminf(fminf(sd[r], os), fmaxf(ob, bd[r]));
      bd[r] = take ? ob : bd[r];
      bi[r] = take ? oi : bi[r];
    }
  }

  __shared__ float redb[64][2], reds[64][2];
  __shared__ int   redi[64][2];
  if((lane & 31) == 0){
    #pragma unroll
    for(int r = 0; r < 16; r++){
      int lr = wr*32 + (r&3) + 8*(r>>2) + 4*h;
      redb[lr][wc] = bd[r]; reds[lr][wc] = sd[r]; redi[lr][wc] = bi[r];
    }
  }
  __syncthreads();
  if(tid < 64){
    float b0 = redb[tid][0], b1v = redb[tid][1];
    float s0 = reds[tid][0], s1v = reds[tid][1];
    int   i0 = redi[tid][0], i1v = redi[tid][1];
    bool take = (b1v < b0) || (b1v == b0 && i1v < i0);
    float fs = fminf(fminf(s0, s1v), fmaxf(b0, b1v));
    size_t o = (size_t)chunk*16384 + m0 + tid;
    pbd[o] = take ? b1v : b0;
    pbi[o] = take ? i1v : i0;
    psd[o] = fs;
  }
}

// =========================================================================
// K5r: merge 4 chunk partials per row; write idx outputs; flag close calls.
__global__ void k5r(const float* __restrict__ pbd, const float* __restrict__ psd,
                    const int* __restrict__ pbi, int* __restrict__ idxw,
                    float* __restrict__ out_idx, int* __restrict__ list, int* cnt){
  int row = blockIdx.x*256 + threadIdx.x;  // grid 64
  float b = pbd[row], s = psd[row];
  int i = pbi[row];
  #pragma unroll
  for(int c = 1; c < 4; c++){
    float ob = pbd[(size_t)c*16384 + row];
    float os = psd[(size_t)c*16384 + row];
    int   oi = pbi[(size_t)c*16384 + row];
    bool take = (ob < b) || (ob == b && oi < i);
    s = fminf(fminf(s, os), fmaxf(b, ob));
    b = take ? ob : b;
    i = take ? oi : i;
  }
  idxw[row] = i;
  out_idx[row] = (float)i;
  if(s - b <= EPSGAP){
    int p = atomicAdd(cnt, 1);
    list[p] = row;
  }
}

// =========================================================================
// K5x: exact f32 rescore of flagged rows (full 8192-code scan per row).
__global__ __launch_bounds__(256) void k5x(const float* __restrict__ zn,
    const float* __restrict__ cb, const int* __restrict__ list, const int* cnt,
    int* __restrict__ idxw, float* __restrict__ out_idx){
  __shared__ float zm2[64];
  __shared__ float rb[4]; __shared__ int ri[4];
  int tid = threadIdx.x;
  int n = *cnt;
  for(int e = blockIdx.x; e < n; e += gridDim.x){
    int row = list[e];
    __syncthreads();
    if(tid < 64) zm2[tid] = -2.f * zn[(size_t)row*64 + tid];
    __syncthreads();
    float bdv = 3.4e38f; int biv = 0;
    int j0 = tid*32;
    for(int j = j0; j < j0+32; j++){
      const float* cp = cb + (size_t)j*64;
      float d = 0.f;
      #pragma unroll
      for(int k = 0; k < 64; k++){
        float c = cp[k];
        d = fmaf(c, c, d);
        d = fmaf(c, zm2[k], d);
      }
      if(d < bdv){ bdv = d; biv = j; }   // ascending j keeps lowest index
    }
    #pragma unroll
    for(int m = 1; m <= 32; m <<= 1){
      float ob = __shfl_xor(bdv, m);
      int   oi = __shfl_xor(biv, m);
      if(ob < bdv || (ob == bdv && oi < biv)){ bdv = ob; biv = oi; }
    }
    if((tid & 63) == 0){ rb[tid>>6] = bdv; ri[tid>>6] = biv; }
    __syncthreads();
    if(tid == 0){
      #pragma unroll
      for(int w = 1; w < 4; w++){
        if(rb[w] < bdv || (rb[w] == bdv && ri[w] < biv)){ bdv = rb[w]; biv = ri[w]; }
      }
      idxw[row] = biv;
      out_idx[row] = (float)biv;
    }
  }
}

// =========================================================================
// K_loss: commit loss from final indices
__global__ void k_loss(const float* __restrict__ zn, const float* __restrict__ cb,
                       const int* __restrict__ idxw, float* stats){
  int row = blockIdx.x*256 + threadIdx.x;  // grid 64
  int code = idxw[row];
  const float* cp = cb + (size_t)code*64;
  const float* zp = zn + (size_t)row*64;
  float s = 0.f;
  #pragma unroll
  for(int k = 0; k < 64; k++){
    float dd = cp[k] - zp[k];
    s = fmaf(dd, dd, s);
  }
  float tot = wredsum(s);
  if((threadIdx.x & 63) == 0) atomicAdd(stats + SLOSS, tot);
}

// =========================================================================
// K6: finalize commit loss (f32 output)
__global__ void k6(const float* stats, float* out){
  if(threadIdx.x == 0) out[0] = 2.f * stats[SLOSS] / 1048576.f;
}

// =========================================================================
// K7: transposed conv (lhs_dilation=5, pad12, K=25) via 5 phase-convs
__global__ void k7(const int* __restrict__ idxp, const float* __restrict__ cb,
                   const float* __restrict__ dwtt, float* __restrict__ h4p, float* stats){
  __shared__ float zq[64*40];
  __shared__ float tb[5*64*33];
  __shared__ float ssum[64], ssq[64];
  int tid = threadIdx.x, b = blockIdx.y, u0 = blockIdx.x*32;
  if(tid < 64){ ssum[tid] = 0.f; ssq[tid] = 0.f; }
  {
    int i = tid & 63, ms = tid >> 6;
    for(int m = ms; m < 37; m += 4){
      int u2 = u0 - 2 + m;
      float v = 0.f;
      if(u2 >= 0 && u2 < 2048){
        int code = idxp[b*2048 + u2];
        v = cb[(size_t)code*64 + i];
      }
      zq[i*40 + m] = v;
    }
  }
  __syncthreads();
  int c = tid & 63, uslot = tid >> 6;
  float acc[5][8];
  #pragma unroll
  for(int v = 0; v < 5; v++)
    #pragma unroll
    for(int s = 0; s < 8; s++) acc[v][s] = 0.f;
  const int km[5] = {2,3,4,0,1};
  const int ov[5] = {2,2,2,3,3};
  for(int i = 0; i < 64; i++){
    float z[13];
    #pragma unroll
    for(int j = 0; j < 13; j++) z[j] = zq[i*40 + uslot*8 + j];
    #pragma unroll
    for(int v = 0; v < 5; v++){
      #pragma unroll
      for(int r = 0; r < 5; r++){
        int k = km[v] + 5*r;
        float w = dwtt[(i*25 + k)*64 + c];
        int off = ov[v] - r + 2;
        #pragma unroll
        for(int s = 0; s < 8; s++) acc[v][s] = fmaf(w, z[s+off], acc[v][s]);
      }
    }
  }
  float ls = 0.f, lq = 0.f;
  #pragma unroll
  for(int v = 0; v < 5; v++){
    #pragma unroll
    for(int s = 0; s < 8; s++){
      int u = u0 + uslot*8 + s;
      float a = siluf(acc[v][s]);
      tb[(v*64 + c)*33 + uslot*8 + s] = a;
      if(v == 0 || u < 2047){ ls += a; lq += a*a; }
    }
  }
  atomicAdd(&ssum[c], ls); atomicAdd(&ssq[c], lq);
  __syncthreads();
  if(tid < 64){ atomicAdd(stats+S4+tid, ssum[tid]); atomicAdd(stats+Q4+tid, ssq[tid]); }
  #pragma unroll
  for(int j = 0; j < 40; j++){
    int flat = tid + 256*j;
    int v = flat / 2048;
    int r = flat - v*2048;
    int cc = r >> 5, ur = r & 31;
    int u = u0 + ur;
    if(v == 0 || u < 2047)
      h4p[(((size_t)v*8 + b)*64 + cc)*2048 + u] = tb[(v*64 + cc)*33 + ur];
  }
}

// =========================================================================
// K8: dbn1 normalize + conv (64->64, K=5, pad2) + bias + silu + dbn2 stats
__global__ void k8(const float* __restrict__ h4p, const float* __restrict__ w2d,
                   const float* __restrict__ b2d, const float* __restrict__ g4,
                   const float* __restrict__ bb4, float* __restrict__ h5, float* stats){
  __shared__ float hw[64*136];
  __shared__ float A4[64], B4[64];
  __shared__ float ssum[64], ssq[64];
  int tid = threadIdx.x, b = blockIdx.y, t0 = blockIdx.x*128;
  if(tid < 64){
    float mu = stats[S4+tid]/81888.f;
    float var = stats[Q4+tid]/81888.f - mu*mu;
    float rs = rsqrtf(var + 1e-5f);
    A4[tid] = rs*g4[tid];
    B4[tid] = bb4[tid] - mu*rs*g4[tid];
    ssum[tid] = 0.f; ssq[tid] = 0.f;
  }
  __syncthreads();
  for(int i2 = tid; i2 < 64*132; i2 += 256){
    int ch = i2/132, tt = i2 - ch*132;
    int t = t0 + tt - 2;
    float v = 0.f;
    if(t >= 0 && t < 10236){
      int vv = t % 5, u = t / 5;
      v = h4p[(((size_t)vv*8 + b)*64 + ch)*2048 + u]*A4[ch] + B4[ch];
    }
    hw[ch*136 + tt] = v;
  }
  __syncthreads();
  int t_rel = tid & 127;
  int chalf = __builtin_amdgcn_readfirstlane(tid >> 7);
  int t = t0 + t_rel;
  float acc[32];
  #pragma unroll
  for(int cc = 0; cc < 32; cc++) acc[cc] = b2d[chalf*32 + cc];
  for(int i = 0; i < 64; i++){
    float z0 = hw[i*136 + t_rel],     z1 = hw[i*136 + t_rel + 1],
          z2 = hw[i*136 + t_rel + 2], z3 = hw[i*136 + t_rel + 3],
          z4 = hw[i*136 + t_rel + 4];
    #pragma unroll
    for(int cc = 0; cc < 32; cc++){
      const float* wp = w2d + ((chalf*32 + cc)*64 + i)*5;
      acc[cc] = fmaf(wp[0],z0,fmaf(wp[1],z1,fmaf(wp[2],z2,fmaf(wp[3],z3,fmaf(wp[4],z4,acc[cc])))));
    }
  }
  bool valid = t < 10236;
  #pragma unroll
  for(int cc = 0; cc < 32; cc++){
    int cch = chalf*32 + cc;
    float a = siluf(acc[cc]);
    float av = valid ? a : 0.f;
    float s = wredsum(av), s2 = wredsum(av*av);
    if((tid & 63) == 0){ atomicAdd(&ssum[cch], s); atomicAdd(&ssq[cch], s2); }
    if(valid) h5[((size_t)(b*64 + cch))*10236 + t] = a;
  }
  __syncthreads();
  if(tid < 64){ atomicAdd(stats+S5+tid, ssum[tid]); atomicAdd(stats+Q5+tid, ssq[tid]); }
}

// =========================================================================
// K9: dbn2 normalize + 1x1 conv (64->1) + bias, pad to 10240, f32 recon
__global__ void k9(const float* __restrict__ h5, const float* __restrict__ w3,
                   const float* __restrict__ b3, const float* __restrict__ g5,
                   const float* __restrict__ bb5, const float* stats,
                   float* __restrict__ out){
  __shared__ float WA[64], WB[64];
  int tid = threadIdx.x;
  if(tid < 64){
    float mu = stats[S5+tid]/81888.f;
    float var = stats[Q5+tid]/81888.f - mu*mu;
    float rs = rsqrtf(var + 1e-5f);
    float A = rs*g5[tid], B = bb5[tid] - mu*rs*g5[tid];
    float w = w3[tid];
    WA[tid] = w*A; WB[tid] = w*B;
  }
  __syncthreads();
  int b = blockIdx.y;
  int t = blockIdx.x*256 + tid;
  float acc = b3[0];
  if(t < 10236){
    const float* hp = h5 + (size_t)(b*64)*10236 + t;
    #pragma unroll
    for(int c = 0; c < 64; c++) acc += WA[c]*hp[(size_t)c*10236] + WB[c];
  } else acc = 0.f;
  out[b*10240 + t] = acc;
}

// =========================================================================
extern "C" void kernel_launch(void* const* d_in, const int* in_sizes, int n_in,
                              void* d_out, int out_size, void* d_ws, size_t ws_size,
                              hipStream_t stream){
  const float* x   = (const float*)d_in[0];
  const float* ew1 = (const float*)d_in[1];
  const float* eb1 = (const float*)d_in[2];
  const float* g1  = (const float*)d_in[3];
  const float* bb1 = (const float*)d_in[4];
  const float* ew2 = (const float*)d_in[5];
  const float* eb2 = (const float*)d_in[6];
  const float* g2  = (const float*)d_in[7];
  const float* bb2 = (const float*)d_in[8];
  const float* ew3 = (const float*)d_in[9];
  const float* eb3 = (const float*)d_in[10];
  const float* g3  = (const float*)d_in[11];
  const float* bb3 = (const float*)d_in[12];
  const float* cb  = (const float*)d_in[13];
  const float* dwt = (const float*)d_in[14];
  const float* g4  = (const float*)d_in[15];
  const float* bb4 = (const float*)d_in[16];
  const float* w2d = (const float*)d_in[17];
  const float* b2d = (const float*)d_in[18];
  const float* g5  = (const float*)d_in[19];
  const float* bb5 = (const float*)d_in[20];
  const float* w3d = (const float*)d_in[21];
  const float* b3d = (const float*)d_in[22];

  char* ws = (char*)d_ws;
  // Phase-disjoint overlays:
  //   [0, 5.24M)  h1 (k1->k2)   then cbh/cbl/cnw (k_prep2->k5m)   then h4p (k7->k8)
  //   [5.24M,15.7M) h2 (k2->k3) then part of h4p
  //   [15.7M,19.9M) zn (k3->k_loss)
  //   [21.0M,...) VQ partials/list/cnt (k5m->k5x), dead before k8 writes h5
  float* h1   = (float*)(ws + 0);
  unsigned short* cbh = (unsigned short*)(ws + 0);          // 1,048,576
  unsigned short* cbl = (unsigned short*)(ws + 1048576);    // 1,048,576
  float* cnw  = (float*)(ws + 2097152);                     // 32,768
  float* h2   = (float*)(ws + 5242880);
  float* zn   = (float*)(ws + 15728640);
  float* h4p  = (float*)(ws + 0);
  float* h5   = (float*)(ws + 20971520);
  int*   list = (int*)  (ws + 20971520);                    // 65,536 (overlays h5, time-disjoint)
  int*   cnt  = (int*)  (ws + 21037056);                    // 256
  float* pbd  = (float*)(ws + 21037312);                    // 262,144
  float* psd  = (float*)(ws + 21299456);                    // 262,144
  int*   pbi  = (int*)  (ws + 21561600);                    // 262,144
  float* w3t  = (float*)(ws + 41934848);
  float* dwtt = (float*)(ws + 42139648);
  int*   idxw = (int*)  (ws + 42549248);
  float* stats= (float*)(ws + 42614784);
  if(ws_size < 42616832) return;

  float* out = (float*)d_out;  // f32: [recon 81920][idx 16384][loss 1]

  hipMemsetAsync(stats, 0, NSTATF*4, stream);
  k_prep<<<600, 256, 0, stream>>>(ew3, dwt, w3t, dwtt);
  k1<<<dim3(40,8), 256, 0, stream>>>(x, ew1, eb1, h1, stats);
  k2<<<dim3(40,8), 256, 0, stream>>>(h1, ew2, eb2, g1, bb1, h2, stats);
  k_prep2<<<32, 256, 0, stream>>>(cb, cbh, cbl, cnw, cnt);   // after k2 (overlays h1)
  k3<<<dim3(64,8), 256, 0, stream>>>(h2, w3t, eb3, g2, bb2, zn, stats);
  k3b<<<1024, 256, 0, stream>>>(zn, g3, bb3, stats);
  k5m<<<dim3(4,256), 256, 0, stream>>>(zn, cbh, cbl, cnw, pbd, psd, pbi);
  k5r<<<64, 256, 0, stream>>>(pbd, psd, pbi, idxw, out + 81920, list, cnt);
  k5x<<<256, 256, 0, stream>>>(zn, cb, list, cnt, idxw, out + 81920);
  k_loss<<<64, 256, 0, stream>>>(zn, cb, idxw, stats);
  k6<<<1, 64, 0, stream>>>(stats, out + 98304);
  k7<<<dim3(64,8), 256, 0, stream>>>(idxw, cb, dwtt, h4p, stats);
  k8<<<dim3(80,8), 256, 0, stream>>>(h4p, w2d, b2d, g4, bb4, h5, stats);
  k9<<<dim3(40,8), 256, 0, stream>>>(h5, w3d, b3d, g5, bb5, stats, out);
}